// Round 14
// baseline (1269.879 us; speedup 1.0000x reference)
//
#include <hip/hip_runtime.h>
#include <hip/hip_bf16.h>
#include <stdint.h>

#define T_N 8192
#define K_N 1024
#define D_N 1024
#define LMBDA 5.0f
#define BIGF 3.0e38f
#define CMAX 32
#define THR 26.0f      // 2*lambda + 4 bound + >10 ulp slack (r9-validated)
#define QNAN 0x7FC00000

// ---------------- norms: numpy-pairwise-exact sum of squares per row ----------------
__global__ __launch_bounds__(256) void k_norms(const float* __restrict__ F,
                                               const float* __restrict__ C,
                                               float* __restrict__ sf2,
                                               float* __restrict__ sc2) {
#pragma clang fp contract(off)
  int wave = threadIdx.x >> 6;
  int lane = threadIdx.x & 63;
  int row = blockIdx.x * 4 + wave;
  const float* src;
  float* dst;
  if (row < T_N) { src = F + (size_t)row * D_N; dst = sf2 + row; }
  else           { src = C + (size_t)(row - T_N) * D_N; dst = sc2 + (row - T_N); }
  int leaf = lane >> 3, j = lane & 7;
  const float* p = src + leaf * 128 + j;
  float x = p[0];
  float r = x * x;
#pragma unroll
  for (int i = 1; i < 16; ++i) {
    float y = p[8 * i];
    r = r + y * y;
  }
  r = r + __shfl_xor(r, 1, 64);
  r = r + __shfl_xor(r, 2, 64);
  r = r + __shfl_xor(r, 4, 64);
  r = r + __shfl_xor(r, 8, 64);
  r = r + __shfl_xor(r, 16, 64);
  r = r + __shfl_xor(r, 32, 64);
  if (lane == 0) *dst = r;
}

// ---------------- d2 GEMM: OpenBLAS-faithful f32 (numerics frozen — do not reorder) ----------------
__global__ __launch_bounds__(256) void k_gemm(const float* __restrict__ F,
                                              const float* __restrict__ C,
                                              const float* __restrict__ sf2,
                                              const float* __restrict__ sc2,
                                              float* __restrict__ d2) {
  __shared__ float As[32][68];
  __shared__ float Bs[32][68];
  int t0 = (int)(blockIdx.x >> 4) * 64;
  int k0 = (int)(blockIdx.x & 15) * 64;
  int tid = threadIdx.x;
  int tx = tid & 15, ty = tid >> 4;
  float acc[4][4], p0[4][4], p1[4][4];
#pragma unroll
  for (int i = 0; i < 4; ++i)
#pragma unroll
    for (int j = 0; j < 4; ++j) { acc[i][j] = 0.0f; p0[i][j] = 0.0f; p1[i][j] = 0.0f; }
  int r = tid & 63;
  int cbase = (tid >> 6) * 2;
  for (int d0 = 0; d0 < D_N; d0 += 32) {
    __syncthreads();
#pragma unroll
    for (int p = 0; p < 2; ++p) {
      int c4 = cbase + p;
      float4 va = *(const float4*)&F[(size_t)(t0 + r) * D_N + d0 + c4 * 4];
      As[c4 * 4 + 0][r] = va.x; As[c4 * 4 + 1][r] = va.y;
      As[c4 * 4 + 2][r] = va.z; As[c4 * 4 + 3][r] = va.w;
      float4 vb = *(const float4*)&C[(size_t)(k0 + r) * D_N + d0 + c4 * 4];
      Bs[c4 * 4 + 0][r] = vb.x; Bs[c4 * 4 + 1][r] = vb.y;
      Bs[c4 * 4 + 2][r] = vb.z; Bs[c4 * 4 + 3][r] = vb.w;
    }
    __syncthreads();
#pragma unroll
    for (int d = 0; d < 32; ++d) {
      float4 a = *(const float4*)&As[d][ty * 4];
      float4 b = *(const float4*)&Bs[d][tx * 4];
      acc[0][0] = fmaf(a.x, b.x, acc[0][0]); acc[0][1] = fmaf(a.x, b.y, acc[0][1]);
      acc[0][2] = fmaf(a.x, b.z, acc[0][2]); acc[0][3] = fmaf(a.x, b.w, acc[0][3]);
      acc[1][0] = fmaf(a.y, b.x, acc[1][0]); acc[1][1] = fmaf(a.y, b.y, acc[1][1]);
      acc[1][2] = fmaf(a.y, b.z, acc[1][2]); acc[1][3] = fmaf(a.y, b.w, acc[1][3]);
      acc[2][0] = fmaf(a.z, b.x, acc[2][0]); acc[2][1] = fmaf(a.z, b.y, acc[2][1]);
      acc[2][2] = fmaf(a.z, b.z, acc[2][2]); acc[2][3] = fmaf(a.z, b.w, acc[2][3]);
      acc[3][0] = fmaf(a.w, b.x, acc[3][0]); acc[3][1] = fmaf(a.w, b.y, acc[3][1]);
      acc[3][2] = fmaf(a.w, b.z, acc[3][2]); acc[3][3] = fmaf(a.w, b.w, acc[3][3]);
    }
    if (d0 == 352) {
#pragma unroll
      for (int i = 0; i < 4; ++i)
#pragma unroll
        for (int j = 0; j < 4; ++j) { p0[i][j] = acc[i][j]; acc[i][j] = 0.0f; }
    }
    if (d0 == 736) {
#pragma unroll
      for (int i = 0; i < 4; ++i)
#pragma unroll
        for (int j = 0; j < 4; ++j) { p1[i][j] = acc[i][j]; acc[i][j] = 0.0f; }
    }
  }
  {
#pragma clang fp contract(off)
#pragma unroll
    for (int i = 0; i < 4; ++i) {
      int t = t0 + ty * 4 + i;
      float sa = sf2[t];
      float o[4];
#pragma unroll
      for (int j = 0; j < 4; ++j) {
        float dot = (p0[i][j] + p1[i][j]) + acc[i][j];
        float two = 2.0f * dot;
        o[j] = (sa - two) + sc2[k0 + tx * 4 + j];
      }
      float4 ov; ov.x = o[0]; ov.y = o[1]; ov.z = o[2]; ov.w = o[3];
      *(float4*)&d2[(size_t)t * K_N + k0 + tx * 4] = ov;
    }
  }
}

// ---------------- cand: per row, candidate list {k: d <= dmin+THR} + row dmin ----------------
__global__ __launch_bounds__(256) void k_cand(const float* __restrict__ d2,
                                              int2* __restrict__ cand,
                                              float* __restrict__ dminOut) {
  int wave = threadIdx.x >> 6;
  int lane = threadIdx.x & 63;
  int row = blockIdx.x * 4 + wave;
  const float4* p = (const float4*)(d2 + (size_t)row * K_N + lane * 16);
  float4 v0 = p[0], v1 = p[1], v2 = p[2], v3 = p[3];
  float m = fminf(fminf(fminf(v0.x, v0.y), fminf(v0.z, v0.w)),
                  fminf(fminf(v1.x, v1.y), fminf(v1.z, v1.w)));
  float n = fminf(fminf(fminf(v2.x, v2.y), fminf(v2.z, v2.w)),
                  fminf(fminf(v3.x, v3.y), fminf(v3.z, v3.w)));
  m = fminf(m, n);
  m = fminf(m, __shfl_xor(m, 1, 64));
  m = fminf(m, __shfl_xor(m, 2, 64));
  m = fminf(m, __shfl_xor(m, 4, 64));
  m = fminf(m, __shfl_xor(m, 8, 64));
  m = fminf(m, __shfl_xor(m, 16, 64));
  m = fminf(m, __shfl_xor(m, 32, 64));
  if (lane == 0) dminOut[row] = m;
  float thr = m + THR;
  unsigned flags = 0;
#define TESTC(J, VAL) if ((VAL) <= thr) flags |= (1u << (J));
  TESTC(0, v0.x) TESTC(1, v0.y) TESTC(2, v0.z) TESTC(3, v0.w)
  TESTC(4, v1.x) TESTC(5, v1.y) TESTC(6, v1.z) TESTC(7, v1.w)
  TESTC(8, v2.x) TESTC(9, v2.y) TESTC(10, v2.z) TESTC(11, v2.w)
  TESTC(12, v3.x) TESTC(13, v3.y) TESTC(14, v3.z) TESTC(15, v3.w)
#undef TESTC
  int c = __popc(flags);
  int pre = c;
#pragma unroll
  for (int off = 1; off <= 32; off <<= 1) {
    int t = __shfl_up(pre, off, 64);
    if (lane >= off) pre += t;
  }
  int idx = pre - c;
  int2* rowp = cand + (size_t)row * CMAX;
  int kb = lane * 16;
#define EMITC(J, VAL)                                                        \
  if (flags & (1u << (J))) {                                                 \
    if (idx < CMAX) rowp[idx] = make_int2(kb + (J), __float_as_int(VAL));    \
    ++idx;                                                                   \
  }
  EMITC(0, v0.x) EMITC(1, v0.y) EMITC(2, v0.z) EMITC(3, v0.w)
  EMITC(4, v1.x) EMITC(5, v1.y) EMITC(6, v1.z) EMITC(7, v1.w)
  EMITC(8, v2.x) EMITC(9, v2.y) EMITC(10, v2.z) EMITC(11, v2.w)
  EMITC(12, v3.x) EMITC(13, v3.y) EMITC(14, v3.z) EMITC(15, v3.w)
#undef EMITC
}

// ---------------- prev2: per-pair lane data for the G=2 pass1 ----------------
__global__ __launch_bounds__(256) void k_prev2(const int2* __restrict__ cand,
                                               int2* __restrict__ pairbuf) {
  __shared__ int km1[4][32];
  __shared__ int kt0[4][32];
  __shared__ int dt0[4][32];
  int w = threadIdx.x >> 6, lane = threadIdx.x & 63;
  int p = blockIdx.x * 4 + w;
  int t0 = 2 * p, t1 = 2 * p + 1, tm1 = t0 - 1;
  if (lane < 32) {
    int2 c0 = cand[(size_t)t0 * CMAX + lane];
    kt0[w][lane] = c0.x; dt0[w][lane] = c0.y;
  } else {
    int j = lane - 32;
    km1[w][j] = (p > 0) ? cand[(size_t)tm1 * CMAX + j].x : -2;
  }
  __syncthreads();
  int2 out;
  if (lane < 32) {
    int2 c1 = cand[(size_t)t1 * CMAX + lane];
    int k1 = c1.x;
    int pp2 = -4, d0 = QNAN;
    bool in0 = false;
#pragma unroll
    for (int i = 0; i < 32; ++i) if (kt0[w][i] == k1) { d0 = dt0[w][i]; in0 = true; }
#pragma unroll
    for (int i = 0; i < 32; ++i) if (km1[w][i] == k1) pp2 = i * 4;
    if (!in0 || k1 < 0) { pp2 = -4; d0 = (k1 < 0 || !in0) ? QNAN : d0; }
    out = make_int2(pp2, d0);
  } else {
    int i0 = lane - 32;
    int k0 = kt0[w][i0];
    int d0 = dt0[w][i0];
    int pp = -4;
#pragma unroll
    for (int i = 0; i < 32; ++i) if (km1[w][i] == k0) pp = i * 4;
    if (k0 < 0) pp = -4;   // sentinel slot (d0 already NaN)
    out = make_int2(pp, d0);
  }
  pairbuf[(size_t)p * 64 + lane] = out;
}

// ---------------- DPP min per 32-lane half (lane 31: lower half; lane 63: upper half) --------
__device__ __forceinline__ float dpp_min32(float x) {
  int t;
  t = __builtin_amdgcn_update_dpp(__float_as_int(x), __float_as_int(x), 0x111, 0xF, 0xF, false);
  x = fminf(x, __int_as_float(t));
  t = __builtin_amdgcn_update_dpp(__float_as_int(x), __float_as_int(x), 0x112, 0xF, 0xF, false);
  x = fminf(x, __int_as_float(t));
  t = __builtin_amdgcn_update_dpp(__float_as_int(x), __float_as_int(x), 0x114, 0xF, 0xF, false);
  x = fminf(x, __int_as_float(t));
  t = __builtin_amdgcn_update_dpp(__float_as_int(x), __float_as_int(x), 0x118, 0xF, 0xF, false);
  x = fminf(x, __int_as_float(t));
  t = __builtin_amdgcn_update_dpp(__float_as_int(x), __float_as_int(x), 0x142, 0xF, 0xF, false); // row_bcast:15
  x = fminf(x, __int_as_float(t));
  return x;
}
__device__ __forceinline__ float rdlane(float x, int l) {
  return __int_as_float(__builtin_amdgcn_readlane(__float_as_int(x), l));
}

// ---------------- pass1: G=2 sparse alpha chain, gather pipelined ONE PAIR ahead -----------
// Identical FP math to r12/r13 (HW-validated). Restructured schedule:
//   iter p consumes gathers issued at iter p-1 (fp = min(g1, g2 + a_{2p-2})),
//   computes chains/mab, then ISSUES the gathers for pair p+1 (payload mab, d1).
// The bpermute latency (~245 cy) is covered by the reduce + finalize + next-iter
// prologue instead of sitting exposed inside one iteration.
__global__ __launch_bounds__(64, 1) void k_pass1(const int2* __restrict__ pairbuf,
                                                 const int2* __restrict__ cand,
                                                 const float* __restrict__ dminArr,
                                                 float* __restrict__ alphaOut) {
  const int lane = threadIdx.x;
  const int2* basep = pairbuf + lane;
  const int2* basec = cand + (lane & 31);
  int2 rg[8], rgc[8];
#pragma unroll
  for (int u = 0; u < 8; ++u) {
    rg[u] = basep[(size_t)u * 64];
    rgc[u] = basec[(size_t)(2 * u + 1) * CMAX];
  }
  int g1 = 0, g2 = 0;       // in-flight gathers for pair p (unused when ppb<0, e.g. p=0)
  float alpha = 0.0f;       // entering iter p: a_{2p-2}
  float redAB = 0.0f;       // pending reduce; lane31 = P_mab of pair p-1
  float dmT1prev = 0.0f;    // dmin_{2p-1}
  float areg = 0.0f;
  float dmv_next = dminArr[lane];
  const int NP = T_N / 2;
  for (int pb32 = 0; pb32 < NP; pb32 += 32) {
    float dmv = dmv_next;
    int nb = pb32 + 32; if (nb >= NP) nb = 0;
    dmv_next = dminArr[2 * nb + lane];
    for (int pb8 = 0; pb8 < 32; pb8 += 8) {
#pragma unroll
      for (int u = 0; u < 8; ++u) {
        int p = pb32 + pb8 + u;
        int2 pv = rg[u];
        int2 cv = rgc[u];
        float aEnter = alpha;                       // a_{2p-2}
        // consume gathers issued at iter p-1: fp = f_{2p-1}[slot k]
        float fp = (pv.x < 0) ? BIGF
                              : fminf(__int_as_float(g1), __int_as_float(g2) + aEnter);
        // prefetch pair p+8 into ring slot u
        int pn8 = p + 8; if (pn8 > NP - 1) pn8 = NP - 1;
        rg[u] = basep[(size_t)pn8 * 64];
        rgc[u] = basec[(size_t)(2 * pn8 + 1) * CMAX];
        // finalize a_{2p-1} (independent of fp)
        float Pab = rdlane(redAB, 31);
        alpha = fminf(Pab, dmT1prev + aEnter);      // a_{2p-1}
        int posA = 2 * p - 1;
        if (posA >= 0) {
          areg = ((posA & 63) == lane) ? alpha : areg;
          if ((posA & 63) == 63) alphaOut[(posA & ~63) + lane] = areg;
        }
        int r0 = 2 * (pb8 + u);
        float dm0 = rdlane(dmv, r0);
        float dm1 = rdlane(dmv, r0 + 1);
        // chains for pair p
        float d0 = __int_as_float(pv.y);
        float d1 = __int_as_float(cv.y);
        float v0 = d0 + (fp - LMBDA);        // lanes<32: A0 ; lanes>=32: pre_t0
        float A1 = d1 + (v0 - LMBDA);
        float B0 = d0 + alpha;               // uses a_{2p-1}
        float B1 = d1 + (B0 - LMBDA);
        float mab = fminf(A1, B1);
        // ISSUE gathers for pair p+1 now (addresses from resident ring slot)
        int2 pvn = rg[(u + 1) & 7];
        g1 = __builtin_amdgcn_ds_bpermute(pvn.x, __float_as_int(mab));
        g2 = __builtin_amdgcn_ds_bpermute(pvn.x, cv.y);
        __builtin_amdgcn_sched_barrier(0);   // pin issues before the reduce
        // reduce + a_{2p}
        float x = (lane < 32) ? mab : v0;
        float red = dpp_min32(x);
        float Pp0 = rdlane(red, 63);         // min pre_t0 over t0 slots
        float a0 = fminf(Pp0, dm0 + alpha);  // a_{2p}
        areg = (((2 * p) & 63) == lane) ? a0 : areg;
        redAB = red;                          // lane 31 = P_mab
        dmT1prev = dm1;
        alpha = a0;
      }
    }
  }
  // epilogue: a_{T-1}
  float Pab = rdlane(redAB, 31);
  alpha = fminf(Pab, dmT1prev + alpha);
  areg = (lane == 63) ? alpha : areg;
  alphaOut[(T_N - 64) + lane] = areg;
}

// ---------------- pass2: chunked warm-start replay per k (validated r1 == full-history r2) ----------------
#define CH 512
#define WARM 64
__global__ __launch_bounds__(256) void k_pass2(const float* __restrict__ d2,
                                               const float* __restrict__ AOUT,
                                               unsigned* __restrict__ pack) {
  int kb = blockIdx.x & 3;
  int tc = blockIdx.x >> 2;
  int k = kb * 256 + threadIdx.x;
  int ts = tc * CH;
  int start = ts - WARM; if (start < 0) start = 0;
  int end = ts + CH;
  __shared__ float lal[CH + WARM + 1];
  for (int i = threadIdx.x; i < end - start + 1; i += 256) {
    int idx = start - 1 + i;
    lal[i] = (idx < 0) ? 0.0f : AOUT[idx];
  }
  __syncthreads();
  float f = BIGF;
  unsigned s = 0;
#pragma unroll 4
  for (int tau = start; tau < end; ++tau) {
    float a_in = lal[tau - start];
    float d = d2[(size_t)tau * K_N + k];
    float ext = f - LMBDA;
    if (a_in < ext) s = (unsigned)tau;
    f = d + fminf(a_in, ext);
    if (tau >= ts) {
      float a_out = lal[tau - start + 1];
      if (f == a_out) atomicMin(&pack[tau], ((unsigned)k << 13) | s);
    }
  }
}

// ---------------- backtrack: ballot run-skip serial chase + parallel fill (validated r1) ----------------
__global__ __launch_bounds__(256) void k_backtrack(const unsigned* __restrict__ pack,
                                                   unsigned* __restrict__ unitsWs,
                                                   float* __restrict__ outUnits) {
  __shared__ unsigned lp[T_N];
  __shared__ unsigned long long msk[T_N / 64];
  int tid = threadIdx.x;
  for (int i = tid * 4; i < T_N; i += 1024) {
    *(uint4*)&lp[i] = *(const uint4*)&pack[i];
  }
  __syncthreads();
  if (tid < 64) {
    int lane = tid;
    int cur = T_N;
    for (int B = T_N - 64; B >= 0; B -= 64) {
      unsigned long long marks = 0ull;
      if (cur > B) {
        unsigned pk = lp[B + lane];
        int bv = (int)(pk & 8191u);
        unsigned long long run = __ballot(bv == B + lane);
        while (cur > B) {
          int L = cur - 1 - B;
          unsigned long long below = (L == 63) ? ~0ull : ((1ull << (L + 1)) - 1ull);
          unsigned long long nz = (~run) & below;
          if (nz == 0ull) { marks |= below; cur = B; break; }
          int j = 63 - __builtin_clzll(nz);
          marks |= below & ~((1ull << j) - 1ull);
          int nb = __builtin_amdgcn_readlane(bv, j);
          cur = nb;
          if (cur > B + j) cur = B + j;
        }
      }
      if (lane == 0) msk[B >> 6] = marks;
    }
  }
  __syncthreads();
  for (int p = tid; p < T_N; p += 256) {
    int w = p >> 6;
    unsigned long long m = msk[w] & (~0ull << (p & 63));
    while (m == 0ull) { ++w; m = msk[w]; }
    int idx = (w << 6) + (int)__builtin_ctzll(m);
    unsigned g = (lp[idx] >> 13) & 1023u;
    unitsWs[p] = g;
    outUnits[p] = (float)g;
  }
}

// ---------------- gather: quantized[t] = codebook[units[t]] ----------------
__global__ __launch_bounds__(256) void k_gather(const float* __restrict__ C,
                                                const unsigned* __restrict__ unitsWs,
                                                float* __restrict__ out) {
  int t = blockIdx.x;
  unsigned u = unitsWs[t] & 1023u;
  const float4* src = (const float4*)(C + (size_t)u * D_N);
  float4* dst = (float4*)(out + (size_t)t * D_N);
  dst[threadIdx.x] = src[threadIdx.x];
}

extern "C" void kernel_launch(void* const* d_in, const int* in_sizes, int n_in,
                              void* d_out, int out_size, void* d_ws, size_t ws_size,
                              hipStream_t stream) {
  const float* F = (const float*)d_in[0];
  const float* C = (const float*)d_in[1];
  float* out = (float*)d_out;
  float* d2 = out;                                  // reuse quantized region as d2 scratch
  float* outUnits = out + (size_t)T_N * D_N;
  char* ws = (char*)d_ws;
  float* alphaOut = (float*)(ws);                    // 32 KB
  unsigned* pack = (unsigned*)(ws + (32 << 10));     // 32 KB
  unsigned* unitsWs = (unsigned*)(ws + (64 << 10));  // 32 KB
  float* sf2 = (float*)(ws + (96 << 10));            // 32 KB
  float* sc2 = (float*)(ws + (128 << 10));           // 4 KB
  float* dminArr = (float*)(ws + (160 << 10));       // 32 KB
  int2* cand = (int2*)(ws + (1 << 20));              // 2 MB (8192 x 32 x 8B)
  int2* pairbuf = (int2*)(ws + (3 << 20));           // 2 MB (4096 x 64 x 8B)

  k_norms<<<(T_N + K_N) / 4, 256, 0, stream>>>(F, C, sf2, sc2);
  hipMemsetAsync(pack, 0xFF, T_N * sizeof(unsigned), stream);
  hipMemsetAsync(cand, 0xFF, (size_t)T_N * CMAX * sizeof(int2), stream);
  k_gemm<<<(T_N / 64) * (K_N / 64), 256, 0, stream>>>(F, C, sf2, sc2, d2);
  k_cand<<<T_N / 4, 256, 0, stream>>>(d2, cand, dminArr);
  k_prev2<<<(T_N / 2) / 4, 256, 0, stream>>>(cand, pairbuf);
  k_pass1<<<1, 64, 0, stream>>>(pairbuf, cand, dminArr, alphaOut);
  k_pass2<<<(T_N / CH) * 4, 256, 0, stream>>>(d2, alphaOut, pack);
  k_backtrack<<<1, 256, 0, stream>>>(pack, unitsWs, outUnits);
  k_gather<<<T_N, 256, 0, stream>>>(C, unitsWs, out);
}

// Round 15
// 1119.904 us; speedup vs baseline: 1.1339x; 1.1339x over previous
//
#include <hip/hip_runtime.h>
#include <hip/hip_bf16.h>
#include <stdint.h>

#define T_N 8192
#define K_N 1024
#define D_N 1024
#define LMBDA 5.0f
#define BIGF 3.0e38f
#define CMAX 32
#define THR 26.0f      // 2*lambda + 4 bound + >10 ulp slack (r9-validated)
#define QNAN 0x7FC00000

// ---------------- norms: numpy-pairwise-exact sum of squares per row ----------------
__global__ __launch_bounds__(256) void k_norms(const float* __restrict__ F,
                                               const float* __restrict__ C,
                                               float* __restrict__ sf2,
                                               float* __restrict__ sc2) {
#pragma clang fp contract(off)
  int wave = threadIdx.x >> 6;
  int lane = threadIdx.x & 63;
  int row = blockIdx.x * 4 + wave;
  const float* src;
  float* dst;
  if (row < T_N) { src = F + (size_t)row * D_N; dst = sf2 + row; }
  else           { src = C + (size_t)(row - T_N) * D_N; dst = sc2 + (row - T_N); }
  int leaf = lane >> 3, j = lane & 7;
  const float* p = src + leaf * 128 + j;
  float x = p[0];
  float r = x * x;
#pragma unroll
  for (int i = 1; i < 16; ++i) {
    float y = p[8 * i];
    r = r + y * y;
  }
  r = r + __shfl_xor(r, 1, 64);
  r = r + __shfl_xor(r, 2, 64);
  r = r + __shfl_xor(r, 4, 64);
  r = r + __shfl_xor(r, 8, 64);
  r = r + __shfl_xor(r, 16, 64);
  r = r + __shfl_xor(r, 32, 64);
  if (lane == 0) *dst = r;
}

// ---------------- d2 GEMM: OpenBLAS-faithful f32, 128x128 tile / 8x8 microtile ----------------
// Per-output numerics IDENTICAL to r4-validated version: sequential fmaf chain in d-order,
// panel snapshots at d=384/768 combined as ((p0+p1)+p2) via progressive dot=..+acc adds.
#define BT 128
#define BK 128
#define DK 16
__global__ __launch_bounds__(256) void k_gemm(const float* __restrict__ F,
                                              const float* __restrict__ C,
                                              const float* __restrict__ sf2,
                                              const float* __restrict__ sc2,
                                              float* __restrict__ d2) {
  __shared__ float As[DK][BT + 4];
  __shared__ float Bs[DK][BK + 4];
  int t0 = (int)(blockIdx.x >> 3) * BT;
  int k0 = (int)(blockIdx.x & 7) * BK;
  int tid = threadIdx.x;
  int tx = tid & 15, ty = tid >> 4;
  float dot[8][8], acc[8][8];
#pragma unroll
  for (int i = 0; i < 8; ++i)
#pragma unroll
    for (int j = 0; j < 8; ++j) { dot[i][j] = 0.0f; acc[i][j] = 0.0f; }
  int r = tid >> 1;
  int cb = (tid & 1) * 8;
  for (int d0 = 0; d0 < D_N; d0 += DK) {
    __syncthreads();
    {
      const float* fa = &F[(size_t)(t0 + r) * D_N + d0 + cb];
      float4 a0 = *(const float4*)fa;
      float4 a1 = *(const float4*)(fa + 4);
      As[cb + 0][r] = a0.x; As[cb + 1][r] = a0.y; As[cb + 2][r] = a0.z; As[cb + 3][r] = a0.w;
      As[cb + 4][r] = a1.x; As[cb + 5][r] = a1.y; As[cb + 6][r] = a1.z; As[cb + 7][r] = a1.w;
      const float* fb = &C[(size_t)(k0 + r) * D_N + d0 + cb];
      float4 b0 = *(const float4*)fb;
      float4 b1 = *(const float4*)(fb + 4);
      Bs[cb + 0][r] = b0.x; Bs[cb + 1][r] = b0.y; Bs[cb + 2][r] = b0.z; Bs[cb + 3][r] = b0.w;
      Bs[cb + 4][r] = b1.x; Bs[cb + 5][r] = b1.y; Bs[cb + 6][r] = b1.z; Bs[cb + 7][r] = b1.w;
    }
    __syncthreads();
#pragma unroll
    for (int d = 0; d < DK; ++d) {
      float4 a0 = *(const float4*)&As[d][ty * 8];
      float4 a1 = *(const float4*)&As[d][ty * 8 + 4];
      float4 b0 = *(const float4*)&Bs[d][tx * 8];
      float4 b1 = *(const float4*)&Bs[d][tx * 8 + 4];
      float av[8] = {a0.x, a0.y, a0.z, a0.w, a1.x, a1.y, a1.z, a1.w};
      float bv[8] = {b0.x, b0.y, b0.z, b0.w, b1.x, b1.y, b1.z, b1.w};
#pragma unroll
      for (int i = 0; i < 8; ++i)
#pragma unroll
        for (int j = 0; j < 8; ++j)
          acc[i][j] = fmaf(av[i], bv[j], acc[i][j]);
    }
    if (d0 == 368) {      // end of panel [0,384): dot = p0, restart chain
#pragma unroll
      for (int i = 0; i < 8; ++i)
#pragma unroll
        for (int j = 0; j < 8; ++j) { dot[i][j] = acc[i][j]; acc[i][j] = 0.0f; }
    }
    if (d0 == 752) {      // end of panel [384,768): dot = p0 + p1 (rounded add)
#pragma unroll
      for (int i = 0; i < 8; ++i)
#pragma unroll
        for (int j = 0; j < 8; ++j) { dot[i][j] = dot[i][j] + acc[i][j]; acc[i][j] = 0.0f; }
    }
  }
  {
#pragma clang fp contract(off)
#pragma unroll
    for (int i = 0; i < 8; ++i) {
      int t = t0 + ty * 8 + i;
      float sa = sf2[t];
      float o[8];
#pragma unroll
      for (int j = 0; j < 8; ++j) {
        float dsum = dot[i][j] + acc[i][j];      // ((p0+p1)+p2), rounded adds
        float two = 2.0f * dsum;                 // exact
        o[j] = (sa - two) + sc2[k0 + tx * 8 + j];
      }
      float4 o0; o0.x = o[0]; o0.y = o[1]; o0.z = o[2]; o0.w = o[3];
      float4 o1; o1.x = o[4]; o1.y = o[5]; o1.z = o[6]; o1.w = o[7];
      float* dp = &d2[(size_t)t * K_N + k0 + tx * 8];
      *(float4*)dp = o0;
      *(float4*)(dp + 4) = o1;
    }
  }
}

// ---------------- cand: per row, candidate list {k: d <= dmin+THR} + row dmin ----------------
__global__ __launch_bounds__(256) void k_cand(const float* __restrict__ d2,
                                              int2* __restrict__ cand,
                                              float* __restrict__ dminOut) {
  int wave = threadIdx.x >> 6;
  int lane = threadIdx.x & 63;
  int row = blockIdx.x * 4 + wave;
  const float4* p = (const float4*)(d2 + (size_t)row * K_N + lane * 16);
  float4 v0 = p[0], v1 = p[1], v2 = p[2], v3 = p[3];
  float m = fminf(fminf(fminf(v0.x, v0.y), fminf(v0.z, v0.w)),
                  fminf(fminf(v1.x, v1.y), fminf(v1.z, v1.w)));
  float n = fminf(fminf(fminf(v2.x, v2.y), fminf(v2.z, v2.w)),
                  fminf(fminf(v3.x, v3.y), fminf(v3.z, v3.w)));
  m = fminf(m, n);
  m = fminf(m, __shfl_xor(m, 1, 64));
  m = fminf(m, __shfl_xor(m, 2, 64));
  m = fminf(m, __shfl_xor(m, 4, 64));
  m = fminf(m, __shfl_xor(m, 8, 64));
  m = fminf(m, __shfl_xor(m, 16, 64));
  m = fminf(m, __shfl_xor(m, 32, 64));
  if (lane == 0) dminOut[row] = m;
  float thr = m + THR;
  unsigned flags = 0;
#define TESTC(J, VAL) if ((VAL) <= thr) flags |= (1u << (J));
  TESTC(0, v0.x) TESTC(1, v0.y) TESTC(2, v0.z) TESTC(3, v0.w)
  TESTC(4, v1.x) TESTC(5, v1.y) TESTC(6, v1.z) TESTC(7, v1.w)
  TESTC(8, v2.x) TESTC(9, v2.y) TESTC(10, v2.z) TESTC(11, v2.w)
  TESTC(12, v3.x) TESTC(13, v3.y) TESTC(14, v3.z) TESTC(15, v3.w)
#undef TESTC
  int c = __popc(flags);
  int pre = c;
#pragma unroll
  for (int off = 1; off <= 32; off <<= 1) {
    int t = __shfl_up(pre, off, 64);
    if (lane >= off) pre += t;
  }
  int idx = pre - c;
  int2* rowp = cand + (size_t)row * CMAX;
  int kb = lane * 16;
#define EMITC(J, VAL)                                                        \
  if (flags & (1u << (J))) {                                                 \
    if (idx < CMAX) rowp[idx] = make_int2(kb + (J), __float_as_int(VAL));    \
    ++idx;                                                                   \
  }
  EMITC(0, v0.x) EMITC(1, v0.y) EMITC(2, v0.z) EMITC(3, v0.w)
  EMITC(4, v1.x) EMITC(5, v1.y) EMITC(6, v1.z) EMITC(7, v1.w)
  EMITC(8, v2.x) EMITC(9, v2.y) EMITC(10, v2.z) EMITC(11, v2.w)
  EMITC(12, v3.x) EMITC(13, v3.y) EMITC(14, v3.z) EMITC(15, v3.w)
#undef EMITC
}

// ---------------- prev2: per-pair lane data for the G=2 pass1 ----------------
__global__ __launch_bounds__(256) void k_prev2(const int2* __restrict__ cand,
                                               int2* __restrict__ pairbuf) {
  __shared__ int km1[4][32];
  __shared__ int kt0[4][32];
  __shared__ int dt0[4][32];
  int w = threadIdx.x >> 6, lane = threadIdx.x & 63;
  int p = blockIdx.x * 4 + w;
  int t0 = 2 * p, t1 = 2 * p + 1, tm1 = t0 - 1;
  if (lane < 32) {
    int2 c0 = cand[(size_t)t0 * CMAX + lane];
    kt0[w][lane] = c0.x; dt0[w][lane] = c0.y;
  } else {
    int j = lane - 32;
    km1[w][j] = (p > 0) ? cand[(size_t)tm1 * CMAX + j].x : -2;
  }
  __syncthreads();
  int2 out;
  if (lane < 32) {
    int2 c1 = cand[(size_t)t1 * CMAX + lane];
    int k1 = c1.x;
    int pp2 = -4, d0 = QNAN;
    bool in0 = false;
#pragma unroll
    for (int i = 0; i < 32; ++i) if (kt0[w][i] == k1) { d0 = dt0[w][i]; in0 = true; }
#pragma unroll
    for (int i = 0; i < 32; ++i) if (km1[w][i] == k1) pp2 = i * 4;
    if (!in0 || k1 < 0) { pp2 = -4; d0 = (k1 < 0 || !in0) ? QNAN : d0; }
    out = make_int2(pp2, d0);
  } else {
    int i0 = lane - 32;
    int k0 = kt0[w][i0];
    int d0 = dt0[w][i0];
    int pp = -4;
#pragma unroll
    for (int i = 0; i < 32; ++i) if (km1[w][i] == k0) pp = i * 4;
    if (k0 < 0) pp = -4;   // sentinel slot (d0 already NaN)
    out = make_int2(pp, d0);
  }
  pairbuf[(size_t)p * 64 + lane] = out;
}

// ---------------- DPP min per 32-lane half (lane 31: lower half; lane 63: upper half) --------
__device__ __forceinline__ float dpp_min32(float x) {
  int t;
  t = __builtin_amdgcn_update_dpp(__float_as_int(x), __float_as_int(x), 0x111, 0xF, 0xF, false);
  x = fminf(x, __int_as_float(t));
  t = __builtin_amdgcn_update_dpp(__float_as_int(x), __float_as_int(x), 0x112, 0xF, 0xF, false);
  x = fminf(x, __int_as_float(t));
  t = __builtin_amdgcn_update_dpp(__float_as_int(x), __float_as_int(x), 0x114, 0xF, 0xF, false);
  x = fminf(x, __int_as_float(t));
  t = __builtin_amdgcn_update_dpp(__float_as_int(x), __float_as_int(x), 0x118, 0xF, 0xF, false);
  x = fminf(x, __int_as_float(t));
  t = __builtin_amdgcn_update_dpp(__float_as_int(x), __float_as_int(x), 0x142, 0xF, 0xF, false); // row_bcast:15
  x = fminf(x, __int_as_float(t));
  return x;
}
__device__ __forceinline__ float rdlane(float x, int l) {
  return __int_as_float(__builtin_amdgcn_readlane(__float_as_int(x), l));
}

// ---------------- pass1: G=2 sparse alpha chain (exact r12 kernel, HW-validated 573 us) ----
__global__ __launch_bounds__(64, 1) void k_pass1(const int2* __restrict__ pairbuf,
                                                 const int2* __restrict__ cand,
                                                 const float* __restrict__ dminArr,
                                                 float* __restrict__ alphaOut) {
  const int lane = threadIdx.x;
  const int2* basep = pairbuf + lane;
  const int2* basec = cand + (lane & 31);
  int2 rg[8], rgc[8];
#pragma unroll
  for (int u = 0; u < 8; ++u) {
    rg[u] = basep[(size_t)u * 64];
    rgc[u] = basec[(size_t)(2 * u + 1) * CMAX];
  }
  float fstate = BIGF;      // f_{2p-1} at lanes 0-31
  float alpha = 0.0f;       // after finalize: a_{2p-1}; after pair body: a_{2p}
  float redAB = 0.0f;       // pending lane-31 reduce (P_AB1 of previous pair)
  float dmT1prev = 0.0f;    // dmin_{2p-1}
  float areg = 0.0f;
  float dmv_next = dminArr[lane];
  const int NP = T_N / 2;
  for (int pb32 = 0; pb32 < NP; pb32 += 32) {
    float dmv = dmv_next;
    int nb = pb32 + 32; if (nb >= NP) nb = 0;
    dmv_next = dminArr[2 * nb + lane];
    for (int pb8 = 0; pb8 < 32; pb8 += 8) {
#pragma unroll
      for (int u = 0; u < 8; ++u) {
        int p = pb32 + pb8 + u;
        int2 pv = rg[u];
        int2 cv = rgc[u];
        // issue the pair's single bpermute first (longest latency)
        int fpb = __builtin_amdgcn_ds_bpermute(pv.x, __float_as_int(fstate));
        // prefetch pair p+8
        int pn = p + 8; if (pn > NP - 1) pn = NP - 1;
        rg[u] = basep[(size_t)pn * 64];
        rgc[u] = basec[(size_t)(2 * pn + 1) * CMAX];
        // finalize a_{2p-1} (overlaps bpermute)
        float Pab = rdlane(redAB, 31);
        alpha = fminf(Pab, dmT1prev + alpha);
        int posA = 2 * p - 1;
        if (posA >= 0) {
          areg = ((posA & 63) == lane) ? alpha : areg;
          if ((posA & 63) == 63) alphaOut[(posA & ~63) + lane] = areg;
        }
        int r0 = 2 * (pb8 + u);
        float dm0 = rdlane(dmv, r0);
        float dm1 = rdlane(dmv, r0 + 1);
        // pair computation
        float fp = (pv.x < 0) ? BIGF : __int_as_float(fpb);
        float d0 = __int_as_float(pv.y);
        float d1 = __int_as_float(cv.y);
        float v0 = d0 + (fp - LMBDA);        // lanes<32: A0 ; lanes>=32: pre_t0
        float A1 = d1 + (v0 - LMBDA);
        float B0 = d0 + alpha;
        float B1 = d1 + (B0 - LMBDA);
        float mab = fminf(A1, B1);
        float x = (lane < 32) ? mab : v0;
        float red = dpp_min32(x);
        float Pp0 = rdlane(red, 63);         // min pre_t0 over t0 slots
        float a0 = fminf(Pp0, dm0 + alpha);  // a_{2p}
        areg = (((2 * p) & 63) == lane) ? a0 : areg;   // even pos: never flushes
        fstate = fminf(mab, d1 + a0);        // f_{2p+1}
        redAB = red;                          // lane 31 = P_AB1, consumed next pair
        dmT1prev = dm1;
        alpha = a0;
      }
    }
  }
  // epilogue: a_{T-1}
  float Pab = rdlane(redAB, 31);
  alpha = fminf(Pab, dmT1prev + alpha);
  areg = (lane == 63) ? alpha : areg;
  alphaOut[(T_N - 64) + lane] = areg;
}

// ---------------- pass2: chunked warm-start replay per k (validated r1 == full-history r2) ----------------
#define CH 512
#define WARM 64
__global__ __launch_bounds__(256) void k_pass2(const float* __restrict__ d2,
                                               const float* __restrict__ AOUT,
                                               unsigned* __restrict__ pack) {
  int kb = blockIdx.x & 3;
  int tc = blockIdx.x >> 2;
  int k = kb * 256 + threadIdx.x;
  int ts = tc * CH;
  int start = ts - WARM; if (start < 0) start = 0;
  int end = ts + CH;
  __shared__ float lal[CH + WARM + 1];
  for (int i = threadIdx.x; i < end - start + 1; i += 256) {
    int idx = start - 1 + i;
    lal[i] = (idx < 0) ? 0.0f : AOUT[idx];
  }
  __syncthreads();
  float f = BIGF;
  unsigned s = 0;
#pragma unroll 4
  for (int tau = start; tau < end; ++tau) {
    float a_in = lal[tau - start];
    float d = d2[(size_t)tau * K_N + k];
    float ext = f - LMBDA;
    if (a_in < ext) s = (unsigned)tau;
    f = d + fminf(a_in, ext);
    if (tau >= ts) {
      float a_out = lal[tau - start + 1];
      if (f == a_out) atomicMin(&pack[tau], ((unsigned)k << 13) | s);
    }
  }
}

// ---------------- backtrack: ballot run-skip serial chase + parallel fill (validated r1) ----------------
__global__ __launch_bounds__(256) void k_backtrack(const unsigned* __restrict__ pack,
                                                   unsigned* __restrict__ unitsWs,
                                                   float* __restrict__ outUnits) {
  __shared__ unsigned lp[T_N];
  __shared__ unsigned long long msk[T_N / 64];
  int tid = threadIdx.x;
  for (int i = tid * 4; i < T_N; i += 1024) {
    *(uint4*)&lp[i] = *(const uint4*)&pack[i];
  }
  __syncthreads();
  if (tid < 64) {
    int lane = tid;
    int cur = T_N;
    for (int B = T_N - 64; B >= 0; B -= 64) {
      unsigned long long marks = 0ull;
      if (cur > B) {
        unsigned pk = lp[B + lane];
        int bv = (int)(pk & 8191u);
        unsigned long long run = __ballot(bv == B + lane);
        while (cur > B) {
          int L = cur - 1 - B;
          unsigned long long below = (L == 63) ? ~0ull : ((1ull << (L + 1)) - 1ull);
          unsigned long long nz = (~run) & below;
          if (nz == 0ull) { marks |= below; cur = B; break; }
          int j = 63 - __builtin_clzll(nz);
          marks |= below & ~((1ull << j) - 1ull);
          int nb = __builtin_amdgcn_readlane(bv, j);
          cur = nb;
          if (cur > B + j) cur = B + j;
        }
      }
      if (lane == 0) msk[B >> 6] = marks;
    }
  }
  __syncthreads();
  for (int p = tid; p < T_N; p += 256) {
    int w = p >> 6;
    unsigned long long m = msk[w] & (~0ull << (p & 63));
    while (m == 0ull) { ++w; m = msk[w]; }
    int idx = (w << 6) + (int)__builtin_ctzll(m);
    unsigned g = (lp[idx] >> 13) & 1023u;
    unitsWs[p] = g;
    outUnits[p] = (float)g;
  }
}

// ---------------- gather: quantized[t] = codebook[units[t]] ----------------
__global__ __launch_bounds__(256) void k_gather(const float* __restrict__ C,
                                                const unsigned* __restrict__ unitsWs,
                                                float* __restrict__ out) {
  int t = blockIdx.x;
  unsigned u = unitsWs[t] & 1023u;
  const float4* src = (const float4*)(C + (size_t)u * D_N);
  float4* dst = (float4*)(out + (size_t)t * D_N);
  dst[threadIdx.x] = src[threadIdx.x];
}

extern "C" void kernel_launch(void* const* d_in, const int* in_sizes, int n_in,
                              void* d_out, int out_size, void* d_ws, size_t ws_size,
                              hipStream_t stream) {
  const float* F = (const float*)d_in[0];
  const float* C = (const float*)d_in[1];
  float* out = (float*)d_out;
  float* d2 = out;                                  // reuse quantized region as d2 scratch
  float* outUnits = out + (size_t)T_N * D_N;
  char* ws = (char*)d_ws;
  float* alphaOut = (float*)(ws);                    // 32 KB
  unsigned* pack = (unsigned*)(ws + (32 << 10));     // 32 KB
  unsigned* unitsWs = (unsigned*)(ws + (64 << 10));  // 32 KB
  float* sf2 = (float*)(ws + (96 << 10));            // 32 KB
  float* sc2 = (float*)(ws + (128 << 10));           // 4 KB
  float* dminArr = (float*)(ws + (160 << 10));       // 32 KB
  int2* cand = (int2*)(ws + (1 << 20));              // 2 MB (8192 x 32 x 8B)
  int2* pairbuf = (int2*)(ws + (3 << 20));           // 2 MB (4096 x 64 x 8B)

  k_norms<<<(T_N + K_N) / 4, 256, 0, stream>>>(F, C, sf2, sc2);
  hipMemsetAsync(pack, 0xFF, T_N * sizeof(unsigned), stream);
  hipMemsetAsync(cand, 0xFF, (size_t)T_N * CMAX * sizeof(int2), stream);
  k_gemm<<<(T_N / BT) * (K_N / BK), 256, 0, stream>>>(F, C, sf2, sc2, d2);
  k_cand<<<T_N / 4, 256, 0, stream>>>(d2, cand, dminArr);
  k_prev2<<<(T_N / 2) / 4, 256, 0, stream>>>(cand, pairbuf);
  k_pass1<<<1, 64, 0, stream>>>(pairbuf, cand, dminArr, alphaOut);
  k_pass2<<<(T_N / CH) * 4, 256, 0, stream>>>(d2, alphaOut, pack);
  k_backtrack<<<1, 256, 0, stream>>>(pack, unitsWs, outUnits);
  k_gather<<<T_N, 256, 0, stream>>>(C, unitsWs, out);
}

// Round 16
// 1032.203 us; speedup vs baseline: 1.2303x; 1.0850x over previous
//
#include <hip/hip_runtime.h>
#include <hip/hip_bf16.h>
#include <stdint.h>

#define T_N 8192
#define K_N 1024
#define D_N 1024
#define LMBDA 5.0f
#define BIGF 3.0e38f
#define CMAX 32
#define THR 26.0f      // 2*lambda + 4 bound + >10 ulp slack (r9-validated)
#define QNAN 0x7FC00000

// ---------------- norms: numpy-pairwise-exact sum of squares per row ----------------
__global__ __launch_bounds__(256) void k_norms(const float* __restrict__ F,
                                               const float* __restrict__ C,
                                               float* __restrict__ sf2,
                                               float* __restrict__ sc2) {
#pragma clang fp contract(off)
  int wave = threadIdx.x >> 6;
  int lane = threadIdx.x & 63;
  int row = blockIdx.x * 4 + wave;
  const float* src;
  float* dst;
  if (row < T_N) { src = F + (size_t)row * D_N; dst = sf2 + row; }
  else           { src = C + (size_t)(row - T_N) * D_N; dst = sc2 + (row - T_N); }
  int leaf = lane >> 3, j = lane & 7;
  const float* p = src + leaf * 128 + j;
  float x = p[0];
  float r = x * x;
#pragma unroll
  for (int i = 1; i < 16; ++i) {
    float y = p[8 * i];
    r = r + y * y;
  }
  r = r + __shfl_xor(r, 1, 64);
  r = r + __shfl_xor(r, 2, 64);
  r = r + __shfl_xor(r, 4, 64);
  r = r + __shfl_xor(r, 8, 64);
  r = r + __shfl_xor(r, 16, 64);
  r = r + __shfl_xor(r, 32, 64);
  if (lane == 0) *dst = r;
}

// ---------------- d2 GEMM: OpenBLAS-faithful f32 64x64 (r4-validated; numerics frozen) -------
__global__ __launch_bounds__(256) void k_gemm(const float* __restrict__ F,
                                              const float* __restrict__ C,
                                              const float* __restrict__ sf2,
                                              const float* __restrict__ sc2,
                                              float* __restrict__ d2) {
  __shared__ float As[32][68];
  __shared__ float Bs[32][68];
  int t0 = (int)(blockIdx.x >> 4) * 64;
  int k0 = (int)(blockIdx.x & 15) * 64;
  int tid = threadIdx.x;
  int tx = tid & 15, ty = tid >> 4;
  float acc[4][4], p0[4][4], p1[4][4];
#pragma unroll
  for (int i = 0; i < 4; ++i)
#pragma unroll
    for (int j = 0; j < 4; ++j) { acc[i][j] = 0.0f; p0[i][j] = 0.0f; p1[i][j] = 0.0f; }
  int r = tid & 63;
  int cbase = (tid >> 6) * 2;
  for (int d0 = 0; d0 < D_N; d0 += 32) {
    __syncthreads();
#pragma unroll
    for (int p = 0; p < 2; ++p) {
      int c4 = cbase + p;
      float4 va = *(const float4*)&F[(size_t)(t0 + r) * D_N + d0 + c4 * 4];
      As[c4 * 4 + 0][r] = va.x; As[c4 * 4 + 1][r] = va.y;
      As[c4 * 4 + 2][r] = va.z; As[c4 * 4 + 3][r] = va.w;
      float4 vb = *(const float4*)&C[(size_t)(k0 + r) * D_N + d0 + c4 * 4];
      Bs[c4 * 4 + 0][r] = vb.x; Bs[c4 * 4 + 1][r] = vb.y;
      Bs[c4 * 4 + 2][r] = vb.z; Bs[c4 * 4 + 3][r] = vb.w;
    }
    __syncthreads();
#pragma unroll
    for (int d = 0; d < 32; ++d) {
      float4 a = *(const float4*)&As[d][ty * 4];
      float4 b = *(const float4*)&Bs[d][tx * 4];
      acc[0][0] = fmaf(a.x, b.x, acc[0][0]); acc[0][1] = fmaf(a.x, b.y, acc[0][1]);
      acc[0][2] = fmaf(a.x, b.z, acc[0][2]); acc[0][3] = fmaf(a.x, b.w, acc[0][3]);
      acc[1][0] = fmaf(a.y, b.x, acc[1][0]); acc[1][1] = fmaf(a.y, b.y, acc[1][1]);
      acc[1][2] = fmaf(a.y, b.z, acc[1][2]); acc[1][3] = fmaf(a.y, b.w, acc[1][3]);
      acc[2][0] = fmaf(a.z, b.x, acc[2][0]); acc[2][1] = fmaf(a.z, b.y, acc[2][1]);
      acc[2][2] = fmaf(a.z, b.z, acc[2][2]); acc[2][3] = fmaf(a.z, b.w, acc[2][3]);
      acc[3][0] = fmaf(a.w, b.x, acc[3][0]); acc[3][1] = fmaf(a.w, b.y, acc[3][1]);
      acc[3][2] = fmaf(a.w, b.z, acc[3][2]); acc[3][3] = fmaf(a.w, b.w, acc[3][3]);
    }
    if (d0 == 352) {
#pragma unroll
      for (int i = 0; i < 4; ++i)
#pragma unroll
        for (int j = 0; j < 4; ++j) { p0[i][j] = acc[i][j]; acc[i][j] = 0.0f; }
    }
    if (d0 == 736) {
#pragma unroll
      for (int i = 0; i < 4; ++i)
#pragma unroll
        for (int j = 0; j < 4; ++j) { p1[i][j] = acc[i][j]; acc[i][j] = 0.0f; }
    }
  }
  {
#pragma clang fp contract(off)
#pragma unroll
    for (int i = 0; i < 4; ++i) {
      int t = t0 + ty * 4 + i;
      float sa = sf2[t];
      float o[4];
#pragma unroll
      for (int j = 0; j < 4; ++j) {
        float dot = (p0[i][j] + p1[i][j]) + acc[i][j];
        float two = 2.0f * dot;
        o[j] = (sa - two) + sc2[k0 + tx * 4 + j];
      }
      float4 ov; ov.x = o[0]; ov.y = o[1]; ov.z = o[2]; ov.w = o[3];
      *(float4*)&d2[(size_t)t * K_N + k0 + tx * 4] = ov;
    }
  }
}

// ---------------- cand: per row, candidate list {k: d <= dmin+THR} + row dmin ----------------
__global__ __launch_bounds__(256) void k_cand(const float* __restrict__ d2,
                                              int2* __restrict__ cand,
                                              float* __restrict__ dminOut) {
  int wave = threadIdx.x >> 6;
  int lane = threadIdx.x & 63;
  int row = blockIdx.x * 4 + wave;
  const float4* p = (const float4*)(d2 + (size_t)row * K_N + lane * 16);
  float4 v0 = p[0], v1 = p[1], v2 = p[2], v3 = p[3];
  float m = fminf(fminf(fminf(v0.x, v0.y), fminf(v0.z, v0.w)),
                  fminf(fminf(v1.x, v1.y), fminf(v1.z, v1.w)));
  float n = fminf(fminf(fminf(v2.x, v2.y), fminf(v2.z, v2.w)),
                  fminf(fminf(v3.x, v3.y), fminf(v3.z, v3.w)));
  m = fminf(m, n);
  m = fminf(m, __shfl_xor(m, 1, 64));
  m = fminf(m, __shfl_xor(m, 2, 64));
  m = fminf(m, __shfl_xor(m, 4, 64));
  m = fminf(m, __shfl_xor(m, 8, 64));
  m = fminf(m, __shfl_xor(m, 16, 64));
  m = fminf(m, __shfl_xor(m, 32, 64));
  if (lane == 0) dminOut[row] = m;
  float thr = m + THR;
  unsigned flags = 0;
#define TESTC(J, VAL) if ((VAL) <= thr) flags |= (1u << (J));
  TESTC(0, v0.x) TESTC(1, v0.y) TESTC(2, v0.z) TESTC(3, v0.w)
  TESTC(4, v1.x) TESTC(5, v1.y) TESTC(6, v1.z) TESTC(7, v1.w)
  TESTC(8, v2.x) TESTC(9, v2.y) TESTC(10, v2.z) TESTC(11, v2.w)
  TESTC(12, v3.x) TESTC(13, v3.y) TESTC(14, v3.z) TESTC(15, v3.w)
#undef TESTC
  int c = __popc(flags);
  int pre = c;
#pragma unroll
  for (int off = 1; off <= 32; off <<= 1) {
    int t = __shfl_up(pre, off, 64);
    if (lane >= off) pre += t;
  }
  int idx = pre - c;
  int2* rowp = cand + (size_t)row * CMAX;
  int kb = lane * 16;
#define EMITC(J, VAL)                                                        \
  if (flags & (1u << (J))) {                                                 \
    if (idx < CMAX) rowp[idx] = make_int2(kb + (J), __float_as_int(VAL));    \
    ++idx;                                                                   \
  }
  EMITC(0, v0.x) EMITC(1, v0.y) EMITC(2, v0.z) EMITC(3, v0.w)
  EMITC(4, v1.x) EMITC(5, v1.y) EMITC(6, v1.z) EMITC(7, v1.w)
  EMITC(8, v2.x) EMITC(9, v2.y) EMITC(10, v2.z) EMITC(11, v2.w)
  EMITC(12, v3.x) EMITC(13, v3.y) EMITC(14, v3.z) EMITC(15, v3.w)
#undef EMITC
}

// ---------------- prev2: per-pair lane data (pp, d0, d1s) for the G=2 pass1 ----------------
// d1s[j] = d_{2p-1}[k_j] — the value formerly fetched by gathering d1prev (static!).
__global__ __launch_bounds__(256) void k_prev2(const int2* __restrict__ cand,
                                               int4* __restrict__ pairbuf) {
  __shared__ int km1k[4][32];
  __shared__ int km1d[4][32];
  __shared__ int kt0k[4][32];
  __shared__ int kt0d[4][32];
  int w = threadIdx.x >> 6, lane = threadIdx.x & 63;
  int p = blockIdx.x * 4 + w;
  int t0 = 2 * p, t1 = 2 * p + 1, tm1 = t0 - 1;
  if (lane < 32) {
    int2 c0 = cand[(size_t)t0 * CMAX + lane];
    kt0k[w][lane] = c0.x; kt0d[w][lane] = c0.y;
  } else {
    int j = lane - 32;
    int2 cm = (p > 0) ? cand[(size_t)tm1 * CMAX + j] : make_int2(-2, 0);
    km1k[w][j] = cm.x; km1d[w][j] = cm.y;
  }
  __syncthreads();
  int4 out;
  if (lane < 32) {
    int2 c1 = cand[(size_t)t1 * CMAX + lane];
    int k1 = c1.x;
    int pp2 = -4, d0 = QNAN, d1s = 0;
    bool in0 = false;
#pragma unroll
    for (int i = 0; i < 32; ++i) if (kt0k[w][i] == k1) { d0 = kt0d[w][i]; in0 = true; }
#pragma unroll
    for (int i = 0; i < 32; ++i) if (km1k[w][i] == k1) { pp2 = i * 4; d1s = km1d[w][i]; }
    if (!in0 || k1 < 0) { pp2 = -4; d0 = QNAN; }
    out = make_int4(pp2, d0, d1s, 0);
  } else {
    int i0 = lane - 32;
    int k0 = kt0k[w][i0];
    int d0 = kt0d[w][i0];
    int pp = -4, d1s = 0;
#pragma unroll
    for (int i = 0; i < 32; ++i) if (km1k[w][i] == k0) { pp = i * 4; d1s = km1d[w][i]; }
    if (k0 < 0) pp = -4;   // sentinel slot (d0 already NaN)
    out = make_int4(pp, d0, d1s, 0);
  }
  pairbuf[(size_t)p * 64 + lane] = out;
}

// ---------------- DPP min per 32-lane half (lane 31: lower half; lane 63: upper half) --------
__device__ __forceinline__ float dpp_min32(float x) {
  int t;
  t = __builtin_amdgcn_update_dpp(__float_as_int(x), __float_as_int(x), 0x111, 0xF, 0xF, false);
  x = fminf(x, __int_as_float(t));
  t = __builtin_amdgcn_update_dpp(__float_as_int(x), __float_as_int(x), 0x112, 0xF, 0xF, false);
  x = fminf(x, __int_as_float(t));
  t = __builtin_amdgcn_update_dpp(__float_as_int(x), __float_as_int(x), 0x114, 0xF, 0xF, false);
  x = fminf(x, __int_as_float(t));
  t = __builtin_amdgcn_update_dpp(__float_as_int(x), __float_as_int(x), 0x118, 0xF, 0xF, false);
  x = fminf(x, __int_as_float(t));
  t = __builtin_amdgcn_update_dpp(__float_as_int(x), __float_as_int(x), 0x142, 0xF, 0xF, false); // row_bcast:15
  x = fminf(x, __int_as_float(t));
  return x;
}
__device__ __forceinline__ float rdlane(float x, int l) {
  return __int_as_float(__builtin_amdgcn_readlane(__float_as_int(x), l));
}

// ---------------- pass1: G=2 sparse chain — bpermute payload is alpha-free mab ------------
// r12 identity (validated): fstate = min(mab, d1 + a_{2p-2}) gathered ==
//   fp = min(gather(mab), gather(d1) + a_{2p-2}); and gather(d1)[j] = d1s[j] (STATIC,
// precomputed in prev2). One bpermute/pair, payload mab — the reduce + alpha-finalize
// run inside the gather's latency shadow; loop-carried cycle = bpermute + ~4 VALU.
__global__ __launch_bounds__(64, 1) void k_pass1(const int4* __restrict__ pairbuf,
                                                 const int2* __restrict__ cand,
                                                 const float* __restrict__ dminArr,
                                                 float* __restrict__ alphaOut) {
  const int lane = threadIdx.x;
  const int4* basep = pairbuf + lane;
  const int2* basec = cand + (lane & 31);
  int4 rg[8];
  int2 rgc[8];
#pragma unroll
  for (int u = 0; u < 8; ++u) {
    rg[u] = basep[(size_t)u * 64];
    rgc[u] = basec[(size_t)(2 * u + 1) * CMAX];
  }
  float mabprev = BIGF;     // mab of previous pair (lanes 0-31 meaningful)
  float alpha = 0.0f;       // entering iter p: a_{2p-2}
  float redAB = 0.0f;       // pending lane-31 reduce (P_AB1 of previous pair)
  float dmT1prev = 0.0f;    // dmin_{2p-1}
  float areg = 0.0f;
  float dmv_next = dminArr[lane];
  const int NP = T_N / 2;
  for (int pb32 = 0; pb32 < NP; pb32 += 32) {
    float dmv = dmv_next;
    int nb = pb32 + 32; if (nb >= NP) nb = 0;
    dmv_next = dminArr[2 * nb + lane];
    for (int pb8 = 0; pb8 < 32; pb8 += 8) {
#pragma unroll
      for (int u = 0; u < 8; ++u) {
        int p = pb32 + pb8 + u;
        int4 pv = rg[u];
        int2 cv = rgc[u];
        float aEnter = alpha;                        // a_{2p-2}
        // the pair's single bpermute: payload mab (alpha-free, ready since last iter)
        int g1 = __builtin_amdgcn_ds_bpermute(pv.x, __float_as_int(mabprev));
        // prefetch pair p+8
        int pn = p + 8; if (pn > NP - 1) pn = NP - 1;
        rg[u] = basep[(size_t)pn * 64];
        rgc[u] = basec[(size_t)(2 * pn + 1) * CMAX];
        // finalize a_{2p-1} (off the gather chain)
        float Pab = rdlane(redAB, 31);
        alpha = fminf(Pab, dmT1prev + aEnter);       // a_{2p-1}
        int posA = 2 * p - 1;
        if (posA >= 0) {
          areg = ((posA & 63) == lane) ? alpha : areg;
          if ((posA & 63) == 63) alphaOut[(posA & ~63) + lane] = areg;
        }
        int r0 = 2 * (pb8 + u);
        float dm0 = rdlane(dmv, r0);
        float dm1 = rdlane(dmv, r0 + 1);
        // fp = min(mab_g, d1s + a_{2p-2})   (== gathered fstate, bit-exact)
        float inj = __int_as_float(pv.z) + aEnter;   // ready before g1 returns
        float fp = (pv.x < 0) ? BIGF : fminf(__int_as_float(g1), inj);
        // pair chains
        float d0 = __int_as_float(pv.y);
        float d1 = __int_as_float(cv.y);
        float v0 = d0 + (fp - LMBDA);        // lanes<32: A0 ; lanes>=32: pre_t0
        float A1 = d1 + (v0 - LMBDA);
        float B0 = d0 + alpha;               // uses a_{2p-1}
        float B1 = d1 + (B0 - LMBDA);
        float mab = fminf(A1, B1);
        float x = (lane < 32) ? mab : v0;
        float red = dpp_min32(x);
        float Pp0 = rdlane(red, 63);         // min pre_t0 over t0 slots
        float a0 = fminf(Pp0, dm0 + alpha);  // a_{2p}
        areg = (((2 * p) & 63) == lane) ? a0 : areg;   // even pos: never flushes
        mabprev = mab;
        redAB = red;                          // lane 31 = P_AB1, consumed next pair
        dmT1prev = dm1;
        alpha = a0;
      }
    }
  }
  // epilogue: a_{T-1}
  float Pab = rdlane(redAB, 31);
  alpha = fminf(Pab, dmT1prev + alpha);
  areg = (lane == 63) ? alpha : areg;
  alphaOut[(T_N - 64) + lane] = areg;
}

// ---------------- pass2: chunked warm-start replay per k (validated r1 == full-history r2) ----------------
#define CH 512
#define WARM 64
__global__ __launch_bounds__(256) void k_pass2(const float* __restrict__ d2,
                                               const float* __restrict__ AOUT,
                                               unsigned* __restrict__ pack) {
  int kb = blockIdx.x & 3;
  int tc = blockIdx.x >> 2;
  int k = kb * 256 + threadIdx.x;
  int ts = tc * CH;
  int start = ts - WARM; if (start < 0) start = 0;
  int end = ts + CH;
  __shared__ float lal[CH + WARM + 1];
  for (int i = threadIdx.x; i < end - start + 1; i += 256) {
    int idx = start - 1 + i;
    lal[i] = (idx < 0) ? 0.0f : AOUT[idx];
  }
  __syncthreads();
  float f = BIGF;
  unsigned s = 0;
#pragma unroll 4
  for (int tau = start; tau < end; ++tau) {
    float a_in = lal[tau - start];
    float d = d2[(size_t)tau * K_N + k];
    float ext = f - LMBDA;
    if (a_in < ext) s = (unsigned)tau;
    f = d + fminf(a_in, ext);
    if (tau >= ts) {
      float a_out = lal[tau - start + 1];
      if (f == a_out) atomicMin(&pack[tau], ((unsigned)k << 13) | s);
    }
  }
}

// ---------------- backtrack: ballot run-skip serial chase + parallel fill (validated r1) ----------------
__global__ __launch_bounds__(256) void k_backtrack(const unsigned* __restrict__ pack,
                                                   unsigned* __restrict__ unitsWs,
                                                   float* __restrict__ outUnits) {
  __shared__ unsigned lp[T_N];
  __shared__ unsigned long long msk[T_N / 64];
  int tid = threadIdx.x;
  for (int i = tid * 4; i < T_N; i += 1024) {
    *(uint4*)&lp[i] = *(const uint4*)&pack[i];
  }
  __syncthreads();
  if (tid < 64) {
    int lane = tid;
    int cur = T_N;
    for (int B = T_N - 64; B >= 0; B -= 64) {
      unsigned long long marks = 0ull;
      if (cur > B) {
        unsigned pk = lp[B + lane];
        int bv = (int)(pk & 8191u);
        unsigned long long run = __ballot(bv == B + lane);
        while (cur > B) {
          int L = cur - 1 - B;
          unsigned long long below = (L == 63) ? ~0ull : ((1ull << (L + 1)) - 1ull);
          unsigned long long nz = (~run) & below;
          if (nz == 0ull) { marks |= below; cur = B; break; }
          int j = 63 - __builtin_clzll(nz);
          marks |= below & ~((1ull << j) - 1ull);
          int nb = __builtin_amdgcn_readlane(bv, j);
          cur = nb;
          if (cur > B + j) cur = B + j;
        }
      }
      if (lane == 0) msk[B >> 6] = marks;
    }
  }
  __syncthreads();
  for (int p = tid; p < T_N; p += 256) {
    int w = p >> 6;
    unsigned long long m = msk[w] & (~0ull << (p & 63));
    while (m == 0ull) { ++w; m = msk[w]; }
    int idx = (w << 6) + (int)__builtin_ctzll(m);
    unsigned g = (lp[idx] >> 13) & 1023u;
    unitsWs[p] = g;
    outUnits[p] = (float)g;
  }
}

// ---------------- gather: quantized[t] = codebook[units[t]] ----------------
__global__ __launch_bounds__(256) void k_gather(const float* __restrict__ C,
                                                const unsigned* __restrict__ unitsWs,
                                                float* __restrict__ out) {
  int t = blockIdx.x;
  unsigned u = unitsWs[t] & 1023u;
  const float4* src = (const float4*)(C + (size_t)u * D_N);
  float4* dst = (float4*)(out + (size_t)t * D_N);
  dst[threadIdx.x] = src[threadIdx.x];
}

extern "C" void kernel_launch(void* const* d_in, const int* in_sizes, int n_in,
                              void* d_out, int out_size, void* d_ws, size_t ws_size,
                              hipStream_t stream) {
  const float* F = (const float*)d_in[0];
  const float* C = (const float*)d_in[1];
  float* out = (float*)d_out;
  float* d2 = out;                                  // reuse quantized region as d2 scratch
  float* outUnits = out + (size_t)T_N * D_N;
  char* ws = (char*)d_ws;
  float* alphaOut = (float*)(ws);                    // 32 KB
  unsigned* pack = (unsigned*)(ws + (32 << 10));     // 32 KB
  unsigned* unitsWs = (unsigned*)(ws + (64 << 10));  // 32 KB
  float* sf2 = (float*)(ws + (96 << 10));            // 32 KB
  float* sc2 = (float*)(ws + (128 << 10));           // 4 KB
  float* dminArr = (float*)(ws + (160 << 10));       // 32 KB
  int2* cand = (int2*)(ws + (1 << 20));              // 2 MB (8192 x 32 x 8B)
  int4* pairbuf = (int4*)(ws + (3 << 20));           // 4 MB (4096 x 64 x 16B)

  k_norms<<<(T_N + K_N) / 4, 256, 0, stream>>>(F, C, sf2, sc2);
  hipMemsetAsync(pack, 0xFF, T_N * sizeof(unsigned), stream);
  hipMemsetAsync(cand, 0xFF, (size_t)T_N * CMAX * sizeof(int2), stream);
  k_gemm<<<(T_N / 64) * (K_N / 64), 256, 0, stream>>>(F, C, sf2, sc2, d2);
  k_cand<<<T_N / 4, 256, 0, stream>>>(d2, cand, dminArr);
  k_prev2<<<(T_N / 2) / 4, 256, 0, stream>>>(cand, pairbuf);
  k_pass1<<<1, 64, 0, stream>>>(pairbuf, cand, dminArr, alphaOut);
  k_pass2<<<(T_N / CH) * 4, 256, 0, stream>>>(d2, alphaOut, pack);
  k_backtrack<<<1, 256, 0, stream>>>(pack, unitsWs, outUnits);
  k_gather<<<T_N, 256, 0, stream>>>(C, unitsWs, out);
}